// Round 9
// baseline (301.820 us; speedup 1.0000x reference)
//
#include <hip/hip_runtime.h>
#include <cstddef>
#include <cstdint>

#define NNODES 50000
#define NEDGES 800000
#define FDIM   256

#define SCAN_BLOCKS 256
#define SCAN_CHUNK  ((NNODES + SCAN_BLOCKS - 1) / SCAN_BLOCKS)   // 196

typedef __attribute__((ext_vector_type(8))) _Float16 f16x8;
typedef __attribute__((ext_vector_type(8))) unsigned short ushort8;
typedef __attribute__((ext_vector_type(4))) float f32x4;

__device__ __forceinline__ float leaky_exp(float a) {
    float e = a > 0.f ? a : 0.2f * a;
    return __expf(e);
}
__device__ __forceinline__ unsigned short f2h(float f) {
    return __builtin_bit_cast(unsigned short, (_Float16)f);
}
__device__ __forceinline__ float hlo(uint32_t u) {
    _Float16 h = __builtin_bit_cast(_Float16, (unsigned short)(u & 0xffffu));
    return (float)h;
}
__device__ __forceinline__ float hhi(uint32_t u) {
    _Float16 h = __builtin_bit_cast(_Float16, (unsigned short)(u >> 16));
    return (float)h;
}
__device__ __forceinline__ float rlanef(float v, int l) {
    return __builtin_bit_cast(float,
        __builtin_amdgcn_readlane(__builtin_bit_cast(int, v), l));
}

// ------- W[256][256] fp32 -> Wt[n][k] f16, coalesced via LDS 64x64 tile -------
// blockIdx.z selects weight 0/1.
__global__ __launch_bounds__(256) void wprep_k(const float* __restrict__ W1,
                                               unsigned short* __restrict__ Wt1,
                                               const float* __restrict__ W2,
                                               unsigned short* __restrict__ Wt2) {
    const float* W = blockIdx.z ? W2 : W1;
    unsigned short* Wt = blockIdx.z ? Wt2 : Wt1;
    __shared__ unsigned short tile[64][68];
    const int kb = blockIdx.x * 64, nb = blockIdx.y * 64;
    const int t = threadIdx.x;
    const int kk = t >> 2, ns = (t & 3) * 16;
    const float* src = W + (size_t)(kb + kk) * 256 + nb + ns;
#pragma unroll
    for (int j = 0; j < 16; j += 4) {
        float4 f = *(const float4*)(src + j);
        tile[kk][ns + j + 0] = f2h(f.x);
        tile[kk][ns + j + 1] = f2h(f.y);
        tile[kk][ns + j + 2] = f2h(f.z);
        tile[kk][ns + j + 3] = f2h(f.w);
    }
    __syncthreads();
    const int nn = t >> 2, ks = (t & 3) * 16;
    ushort8 r0, r1;
#pragma unroll
    for (int j = 0; j < 8; ++j) {
        r0[j] = tile[ks + j][nn];
        r1[j] = tile[ks + 8 + j][nn];
    }
    unsigned short* dst = Wt + (size_t)(nb + nn) * 256 + kb + ks;
    *(ushort8*)(dst + 0) = r0;
    *(ushort8*)(dst + 8) = r1;
}

// --- fused GEMM: C[M,256] = A[M,256] @ Bt^T (f16 out) + attention logit dots ---
template <bool AFP32, int H>
__global__ __launch_bounds__(512) void gemm_fused(const void* __restrict__ Aab,
                                                  const unsigned short* __restrict__ Bt,
                                                  unsigned short* __restrict__ C,
                                                  const float* __restrict__ atts,
                                                  const float* __restrict__ attd,
                                                  float* __restrict__ as_,
                                                  float* __restrict__ ad_,
                                                  int M) {
    __shared__ unsigned short sh[128 * 64 + 256 * 64];   // 48 KB total
    unsigned short* As = sh;                 // 16 KB
    unsigned short* Bs = sh + 128 * 64;      // 32 KB
    const int t = threadIdx.x;
    const int lane = t & 63, wid = t >> 6;
    const int wr = wid >> 2, wc = wid & 3;   // 2x4 waves, each 64x64 out
    const int bm = blockIdx.x * 128;
    f32x4 acc[4][4] = {};
    const int arow = t >> 2, asub = t & 3;   // A: 4 threads/row, 16 k each
    const int brow = t >> 1, bsub = t & 1;   // B: 2 threads/row, 32 k each
    for (int k0 = 0; k0 < 256; k0 += 64) {
        __syncthreads();
        {
            int ga = bm + arow; ga = ga < M ? ga : M - 1;
            if (AFP32) {
                const float* A32 = (const float*)Aab;
#pragma unroll
                for (int s2 = 0; s2 < 2; ++s2) {
                    int slot = asub * 2 + s2;
                    const float* p = A32 + (size_t)ga * 256 + k0 + slot * 8;
                    float4 f0 = *(const float4*)p;
                    float4 f1 = *(const float4*)(p + 4);
                    ushort8 r;
                    r[0] = f2h(f0.x); r[1] = f2h(f0.y); r[2] = f2h(f0.z); r[3] = f2h(f0.w);
                    r[4] = f2h(f1.x); r[5] = f2h(f1.y); r[6] = f2h(f1.z); r[7] = f2h(f1.w);
                    *(ushort8*)(As + arow * 64 + ((slot ^ (arow & 7)) << 3)) = r;
                }
            } else {
                const unsigned short* A16 = (const unsigned short*)Aab;
#pragma unroll
                for (int s2 = 0; s2 < 2; ++s2) {
                    int slot = asub * 2 + s2;
                    uint4 v = *(const uint4*)(A16 + (size_t)ga * 256 + k0 + slot * 8);
                    *(uint4*)(As + arow * 64 + ((slot ^ (arow & 7)) << 3)) = v;
                }
            }
#pragma unroll
            for (int s4 = 0; s4 < 4; ++s4) {
                int slot = bsub * 4 + s4;
                uint4 v = *(const uint4*)(Bt + (size_t)brow * 256 + k0 + slot * 8);
                *(uint4*)(Bs + brow * 64 + ((slot ^ (brow & 7)) << 3)) = v;
            }
        }
        __syncthreads();
#pragma unroll
        for (int ks = 0; ks < 2; ++ks) {
            const int kq = ks * 4 + (lane >> 4);
            f16x8 a[4], b[4];
#pragma unroll
            for (int f = 0; f < 4; ++f) {
                int ra = wr * 64 + f * 16 + (lane & 15);
                a[f] = *(const f16x8*)(As + ra * 64 + ((kq ^ (ra & 7)) << 3));
                int rb = wc * 64 + f * 16 + (lane & 15);
                b[f] = *(const f16x8*)(Bs + rb * 64 + ((kq ^ (rb & 7)) << 3));
            }
#pragma unroll
            for (int mf = 0; mf < 4; ++mf)
#pragma unroll
                for (int nf = 0; nf < 4; ++nf)
                    acc[mf][nf] = __builtin_amdgcn_mfma_f32_16x16x32_f16(
                        a[mf], b[nf], acc[mf][nf], 0, 0, 0);
        }
    }
    const int col0 = wc * 64 + (lane & 15);
    // ---- fused attention-logit partial dots ----
    float sv[4], dv[4];
#pragma unroll
    for (int nf = 0; nf < 4; ++nf) {
        sv[nf] = atts[col0 + nf * 16];
        dv[nf] = attd[col0 + nf * 16];
    }
    const int hsel = (H == 4) ? wc : 0;
    const int row00 = bm + wr * 64 + (lane >> 4) * 4;
#pragma unroll
    for (int mf = 0; mf < 4; ++mf)
#pragma unroll
        for (int r = 0; r < 4; ++r) {
            float ps = 0.f, pd = 0.f;
#pragma unroll
            for (int nf = 0; nf < 4; ++nf) {
                float v = acc[mf][nf][r];
                ps = fmaf(v, sv[nf], ps);
                pd = fmaf(v, dv[nf], pd);
            }
#pragma unroll
            for (int off = 1; off < 16; off <<= 1) {
                ps += __shfl_xor(ps, off);
                pd += __shfl_xor(pd, off);
            }
            int row = row00 + mf * 16 + r;
            if ((lane & 15) == 0 && row < M) {
                unsafeAtomicAdd(&as_[row * H + hsel], ps);
                unsafeAtomicAdd(&ad_[row * H + hsel], pd);
            }
        }
    // ---- coalesced C store via LDS bounce (staging LDS is dead now) ----
    unsigned short* Cs = sh;                 // 64 x 264 ushorts = 33 KB
#pragma unroll 1
    for (int hf = 0; hf < 2; ++hf) {
        __syncthreads();
        if (wr == hf) {
#pragma unroll
            for (int mf = 0; mf < 4; ++mf) {
#pragma unroll
                for (int nf = 0; nf < 4; ++nf) {
#pragma unroll
                    for (int r = 0; r < 4; ++r) {
                        int rl = mf * 16 + (lane >> 4) * 4 + r;
                        int cl = wc * 64 + nf * 16 + (lane & 15);
                        Cs[rl * 264 + cl] = f2h(acc[mf][nf][r]);
                    }
                }
            }
        }
        __syncthreads();
        {
            int rl = t >> 3;                 // 0..63
            int row = bm + hf * 64 + rl;
            int cb = (t & 7) * 8;            // 0..56
            if (row < M) {
#pragma unroll
                for (int j = 0; j < 4; ++j) {
                    ushort8 v = *(const ushort8*)(Cs + rl * 264 + cb + j * 64);
                    *(ushort8*)(C + (size_t)row * FDIM + cb + j * 64) = v;
                }
            }
        }
    }
}

// ---------------- CSR build: histogram -> 3-phase scan -> scatter ----------------
__global__ __launch_bounds__(256) void hist_k(const int* __restrict__ ei,
                                              int* __restrict__ deg) {
    int e = blockIdx.x * 256 + threadIdx.x;
    if (e < NEDGES) atomicAdd(&deg[ei[NEDGES + e]], 1);
}

__global__ __launch_bounds__(256) void scanA_k(const int* __restrict__ deg,
                                               int* __restrict__ bsum) {
    const int b = blockIdx.x, t = threadIdx.x;
    const int i = b * SCAN_CHUNK + t;
    int v = (t < SCAN_CHUNK && i < NNODES) ? deg[i] : 0;
#pragma unroll
    for (int off = 1; off < 64; off <<= 1) v += __shfl_xor(v, off);
    __shared__ int ws[4];
    if ((t & 63) == 0) ws[t >> 6] = v;
    __syncthreads();
    if (t == 0) bsum[b] = ws[0] + ws[1] + ws[2] + ws[3];
}

__global__ __launch_bounds__(256) void scanB_k(const int* __restrict__ bsum,
                                               int* __restrict__ boff,
                                               int* __restrict__ rowptr) {
    const int t = threadIdx.x;
    const int lane = t & 63, wid = t >> 6;
    int orig = bsum[t];
    int v = orig;
#pragma unroll
    for (int off = 1; off < 64; off <<= 1) {
        int u = __shfl_up(v, off);
        if (lane >= off) v += u;
    }
    __shared__ int ws[4], wo[4];
    if (lane == 63) ws[wid] = v;
    __syncthreads();
    if (t == 0) {
        int a = 0;
        for (int k = 0; k < 4; ++k) { wo[k] = a; a += ws[k]; }
        rowptr[NNODES] = a;
    }
    __syncthreads();
    boff[t] = wo[wid] + v - orig;
}

__global__ __launch_bounds__(256) void scanC_k(const int* __restrict__ deg,
                                               const int* __restrict__ boff,
                                               int* __restrict__ rowptr) {
    const int b = blockIdx.x, t = threadIdx.x;
    const int i = b * SCAN_CHUNK + t;
    const bool ok = (t < SCAN_CHUNK && i < NNODES);
    int orig = ok ? deg[i] : 0;
    int v = orig;
    const int lane = t & 63, wid = t >> 6;
#pragma unroll
    for (int off = 1; off < 64; off <<= 1) {
        int u = __shfl_up(v, off);
        if (lane >= off) v += u;
    }
    __shared__ int ws[4], wo[4];
    if (lane == 63) ws[wid] = v;
    __syncthreads();
    if (t == 0) {
        int a = 0;
        for (int k = 0; k < 4; ++k) { wo[k] = a; a += ws[k]; }
    }
    __syncthreads();
    if (ok) rowptr[i] = boff[b] + wo[wid] + v - orig;
}

__global__ __launch_bounds__(256) void scatter_k(const int* __restrict__ ei,
                                                 const int* __restrict__ rowptr,
                                                 int* __restrict__ deg,
                                                 int* __restrict__ ssrc) {
    int e = blockIdx.x * 256 + threadIdx.x;
    if (e >= NEDGES) return;
    int s = ei[e], d = ei[NEDGES + e];
    int old = atomicSub(&deg[d], 1);
    ssrc[rowptr[d + 1] - old] = s;
}

// ---- layer-1 gather (H=4): f16 rows, den in weight phase, bias+ELU, f16 out ----
__global__ __launch_bounds__(256) void gather1_k(const unsigned short* __restrict__ xp,
                                                 const float* __restrict__ as_,
                                                 const float* __restrict__ ad_,
                                                 const int* __restrict__ rowptr,
                                                 const int* __restrict__ ssrc,
                                                 const float* __restrict__ bias,
                                                 unsigned short* __restrict__ out) {
    const int lane = threadIdx.x & 63;
    const int n = blockIdx.x * 4 + (threadIdx.x >> 6);
    if (n >= NNODES) return;
    const int h = lane >> 4;            // head for feature lanes
    const int c = lane << 2;
    const int eloc = lane >> 2;         // strip edge slot (0..15)
    const int hh = lane & 3;            // strip head slot
    const float adW = ad_[n * 4 + hh];
    float a0 = 0.f, a1 = 0.f, a2 = 0.f, a3 = 0.f, den = 0.f;
    const int beg = rowptr[n], end = rowptr[n + 1];
    for (int base = beg; base < end; base += 16) {
        int my_e = base + eloc;
        float wv = 0.f; int sv = 0;
        if (my_e < end) {
            sv = ssrc[my_e];
            wv = leaky_exp(as_[sv * 4 + hh] + adW);
        }
        float dred = wv;
#pragma unroll
        for (int off = 4; off < 64; off <<= 1) dred += __shfl_xor(dred, off);
        den += __shfl(dred, h);
        const int cnt = min(16, end - base);
        int e = 0;
        for (; e + 8 <= cnt; e += 8) {
            uint2 u[8]; float w[8];
#pragma unroll
            for (int q = 0; q < 8; ++q) {
                int sq = __builtin_amdgcn_readlane(sv, (e + q) << 2);
                u[q] = *(const uint2*)(xp + (((unsigned)sq << 8) + (unsigned)c));
                w[q] = __shfl(wv, ((e + q) << 2) | h);
            }
#pragma unroll
            for (int q = 0; q < 8; ++q) {
                a0 = fmaf(hlo(u[q].x), w[q], a0);
                a1 = fmaf(hhi(u[q].x), w[q], a1);
                a2 = fmaf(hlo(u[q].y), w[q], a2);
                a3 = fmaf(hhi(u[q].y), w[q], a3);
            }
        }
        for (; e < cnt; ++e) {
            int sq = __builtin_amdgcn_readlane(sv, e << 2);
            uint2 u0 = *(const uint2*)(xp + (((unsigned)sq << 8) + (unsigned)c));
            float w0 = __shfl(wv, (e << 2) | h);
            a0 = fmaf(hlo(u0.x), w0, a0); a1 = fmaf(hhi(u0.x), w0, a1);
            a2 = fmaf(hlo(u0.y), w0, a2); a3 = fmaf(hhi(u0.y), w0, a3);
        }
    }
    {   // self loop
        float w = leaky_exp(as_[n * 4 + h] + ad_[n * 4 + h]);
        uint2 u = *(const uint2*)(xp + (((unsigned)n << 8) + (unsigned)c));
        a0 = fmaf(hlo(u.x), w, a0); a1 = fmaf(hhi(u.x), w, a1);
        a2 = fmaf(hlo(u.y), w, a2); a3 = fmaf(hhi(u.y), w, a3);
        den += w;
    }
    const float inv = 1.f / (den + 1e-16f);
    float4 b4 = *(const float4*)(bias + c);
    float o[4] = {a0 * inv + b4.x, a1 * inv + b4.y,
                  a2 * inv + b4.z, a3 * inv + b4.w};
#pragma unroll
    for (int j = 0; j < 4; ++j) o[j] = o[j] > 0.f ? o[j] : __expf(o[j]) - 1.f;
    ushort4 r;
    r.x = f2h(o[0]); r.y = f2h(o[1]); r.z = f2h(o[2]); r.w = f2h(o[3]);
    *(ushort4*)(out + (size_t)n * FDIM + c) = r;
}

// ---- layer-2 gather (H=1): 64-edge strips, readlane weights; +BN+LN ----
__global__ __launch_bounds__(256) void gather2_k(const unsigned short* __restrict__ xp,
                                                 const float* __restrict__ as_,
                                                 const float* __restrict__ ad_,
                                                 const int* __restrict__ rowptr,
                                                 const int* __restrict__ ssrc,
                                                 const float* __restrict__ bias,
                                                 const float* __restrict__ bng,
                                                 const float* __restrict__ bnb,
                                                 const float* __restrict__ bnm,
                                                 const float* __restrict__ bnv,
                                                 const float* __restrict__ lng,
                                                 const float* __restrict__ lnb,
                                                 float* __restrict__ out) {
    const int lane = threadIdx.x & 63;
    const int n = blockIdx.x * 4 + (threadIdx.x >> 6);
    if (n >= NNODES) return;
    const int c = lane << 2;
    const float adn = ad_[n];
    float a0 = 0.f, a1 = 0.f, a2 = 0.f, a3 = 0.f, den = 0.f;
    const int beg = rowptr[n], end = rowptr[n + 1];
    for (int base = beg; base < end; base += 64) {
        int my_e = base + lane;
        float wv = 0.f; int sv = 0;
        if (my_e < end) {
            sv = ssrc[my_e];
            wv = leaky_exp(as_[sv] + adn);
        }
        float dred = wv;
#pragma unroll
        for (int off = 1; off < 64; off <<= 1) dred += __shfl_xor(dred, off);
        den += dred;
        const int cnt = min(64, end - base);
        int e = 0;
        for (; e + 8 <= cnt; e += 8) {
            uint2 u[8]; float w[8];
#pragma unroll
            for (int q = 0; q < 8; ++q) {
                int sq = __builtin_amdgcn_readlane(sv, e + q);
                u[q] = *(const uint2*)(xp + (((unsigned)sq << 8) + (unsigned)c));
                w[q] = rlanef(wv, e + q);
            }
#pragma unroll
            for (int q = 0; q < 8; ++q) {
                a0 = fmaf(hlo(u[q].x), w[q], a0);
                a1 = fmaf(hhi(u[q].x), w[q], a1);
                a2 = fmaf(hlo(u[q].y), w[q], a2);
                a3 = fmaf(hhi(u[q].y), w[q], a3);
            }
        }
        for (; e < cnt; ++e) {
            int sq = __builtin_amdgcn_readlane(sv, e);
            uint2 u0 = *(const uint2*)(xp + (((unsigned)sq << 8) + (unsigned)c));
            float w0 = rlanef(wv, e);
            a0 = fmaf(hlo(u0.x), w0, a0); a1 = fmaf(hhi(u0.x), w0, a1);
            a2 = fmaf(hlo(u0.y), w0, a2); a3 = fmaf(hhi(u0.y), w0, a3);
        }
    }
    {   // self loop
        float w = leaky_exp(as_[n] + adn);
        uint2 u = *(const uint2*)(xp + (((unsigned)n << 8) + (unsigned)c));
        a0 = fmaf(hlo(u.x), w, a0); a1 = fmaf(hhi(u.x), w, a1);
        a2 = fmaf(hlo(u.y), w, a2); a3 = fmaf(hhi(u.y), w, a3);
        den += w;
    }
    const float inv = 1.f / (den + 1e-16f);
    float vals[4] = {a0 * inv, a1 * inv, a2 * inv, a3 * inv};
#pragma unroll
    for (int j = 0; j < 4; ++j) {
        float o = vals[j] + bias[c + j];
        o = o > 0.f ? o : __expf(o) - 1.f;                             // ELU
        o = (o - bnm[c + j]) * rsqrtf(bnv[c + j] + 1e-5f) * bng[c + j]
            + bnb[c + j];                                              // BN
        vals[j] = o;
    }
    float s1 = vals[0] + vals[1] + vals[2] + vals[3];
    float s2 = vals[0] * vals[0] + vals[1] * vals[1] +
               vals[2] * vals[2] + vals[3] * vals[3];
#pragma unroll
    for (int off = 1; off < 64; off <<= 1) {
        s1 += __shfl_xor(s1, off);
        s2 += __shfl_xor(s2, off);
    }
    float mu  = s1 * (1.f / 256.f);
    float var = s2 * (1.f / 256.f) - mu * mu;
    float r   = rsqrtf(var + 1e-5f);
#pragma unroll
    for (int j = 0; j < 4; ++j)
        out[(size_t)n * FDIM + c + j] = (vals[j] - mu) * r * lng[c + j] + lnb[c + j];
}

extern "C" void kernel_launch(void* const* d_in, const int* in_sizes, int n_in,
                              void* d_out, int out_size, void* d_ws, size_t ws_size,
                              hipStream_t stream) {
    const float* x      = (const float*)d_in[0];
    const int*   ei     = (const int*)d_in[1];
    const float* W1     = (const float*)d_in[2];
    const float* atts1  = (const float*)d_in[3];
    const float* attd1  = (const float*)d_in[4];
    const float* bias1  = (const float*)d_in[5];
    const float* W2     = (const float*)d_in[6];
    const float* atts2  = (const float*)d_in[7];
    const float* attd2  = (const float*)d_in[8];
    const float* bias2  = (const float*)d_in[9];
    const float* bng    = (const float*)d_in[10];
    const float* bnb    = (const float*)d_in[11];
    const float* bnm    = (const float*)d_in[12];
    const float* bnv    = (const float*)d_in[13];
    const float* lng    = (const float*)d_in[14];
    const float* lnb    = (const float*)d_in[15];

    const size_t NF = (size_t)NNODES * FDIM;
    unsigned short* xpbf = (unsigned short*)d_ws;     // 25.6 MB (xp, both layers)
    unsigned short* xbf  = xpbf + NF;                 // 25.6 MB (h1 f16)
    unsigned short* wt1  = xbf + NF;
    unsigned short* wt2  = wt1 + 65536;
    float* as1   = (float*)(wt2 + 65536);             // N*4
    float* ad1   = as1 + (size_t)NNODES * 4;          // N*4
    float* as2   = ad1 + (size_t)NNODES * 4;          // N
    float* ad2   = as2 + NNODES;                      // N
    int*   deg    = (int*)(ad2 + NNODES);
    int*   rowptr = deg + NNODES;
    int*   bsum   = rowptr + (NNODES + 1);
    int*   boff   = bsum + SCAN_BLOCKS;
    int*   ssrc   = boff + SCAN_BLOCKS;
    float* outf  = (float*)d_out;

    const int gemm_blocks = (NNODES + 127) / 128;     // 391
    const int node_wave_blocks = (NNODES + 3) / 4;
    const int edge_thread_blocks = (NEDGES + 255) / 256;

    // ---- prep: W transpose/convert + CSR + zero logit accumulators ----
    wprep_k<<<dim3(4, 4, 2), 256, 0, stream>>>(W1, wt1, W2, wt2);
    hipMemsetAsync(deg, 0, NNODES * sizeof(int), stream);
    hipMemsetAsync(as1, 0, (size_t)NNODES * 10 * sizeof(float), stream); // as1,ad1,as2,ad2
    hist_k<<<edge_thread_blocks, 256, 0, stream>>>(ei, deg);
    scanA_k<<<SCAN_BLOCKS, 256, 0, stream>>>(deg, bsum);
    scanB_k<<<1, 256, 0, stream>>>(bsum, boff, rowptr);
    scanC_k<<<SCAN_BLOCKS, 256, 0, stream>>>(deg, boff, rowptr);
    scatter_k<<<edge_thread_blocks, 256, 0, stream>>>(ei, rowptr, deg, ssrc);

    // ---- layer 1: GEMM (fp32 A, converts in-kernel) + fused logits ----
    gemm_fused<true, 4><<<gemm_blocks, 512, 0, stream>>>(
        x, wt1, xpbf, atts1, attd1, as1, ad1, NNODES);
    gather1_k<<<node_wave_blocks, 256, 0, stream>>>(xpbf, as1, ad1, rowptr, ssrc,
                                                    bias1, xbf);

    // ---- layer 2: GEMM (f16 A = h1) + fused logits ----
    gemm_fused<false, 1><<<gemm_blocks, 512, 0, stream>>>(
        xbf, wt2, xpbf, atts2, attd2, as2, ad2, NNODES);
    gather2_k<<<node_wave_blocks, 256, 0, stream>>>(xpbf, as2, ad2, rowptr, ssrc,
                                                    bias2, bng, bnb, bnm, bnv,
                                                    lng, lnb, outf);
}

// Round 11
// 291.769 us; speedup vs baseline: 1.0344x; 1.0344x over previous
//
#include <hip/hip_runtime.h>
#include <cstddef>
#include <cstdint>

#define NNODES 50000
#define NEDGES 800000
#define FDIM   256

#define SCAN_BLOCKS 256
#define SCAN_CHUNK  ((NNODES + SCAN_BLOCKS - 1) / SCAN_BLOCKS)   // 196

typedef __attribute__((ext_vector_type(8))) _Float16 f16x8;
typedef __attribute__((ext_vector_type(8))) unsigned short ushort8;
typedef __attribute__((ext_vector_type(4))) float f32x4;

__device__ __forceinline__ float leaky_exp(float a) {
    float e = a > 0.f ? a : 0.2f * a;
    return __expf(e);
}
__device__ __forceinline__ unsigned short f2h(float f) {
    return __builtin_bit_cast(unsigned short, (_Float16)f);
}
__device__ __forceinline__ float hlo(uint32_t u) {
    _Float16 h = __builtin_bit_cast(_Float16, (unsigned short)(u & 0xffffu));
    return (float)h;
}
__device__ __forceinline__ float hhi(uint32_t u) {
    _Float16 h = __builtin_bit_cast(_Float16, (unsigned short)(u >> 16));
    return (float)h;
}

// ---------------- fp32 -> f16 bulk convert (8 elems/thread) ----------------
__global__ __launch_bounds__(256) void cvt_k(const float* __restrict__ in,
                                             unsigned short* __restrict__ out,
                                             int n8) {
    int i = blockIdx.x * 256 + threadIdx.x;
    if (i >= n8) return;
    const float4* p = (const float4*)in + (size_t)i * 2;
    float4 a = p[0], b = p[1];
    ushort8 r;
    r[0] = f2h(a.x); r[1] = f2h(a.y); r[2] = f2h(a.z); r[3] = f2h(a.w);
    r[4] = f2h(b.x); r[5] = f2h(b.y); r[6] = f2h(b.z); r[7] = f2h(b.w);
    *(ushort8*)(out + (size_t)i * 8) = r;
}

// ------------- W[256][256] -> Wt[n][k] f16 (transpose + convert) -------------
__global__ __launch_bounds__(256) void wprep_k(const float* __restrict__ W,
                                               unsigned short* __restrict__ Wt) {
    int n = blockIdx.x, k = threadIdx.x;
    Wt[n * 256 + k] = f2h(W[k * 256 + n]);
}

// --------- f16 MFMA GEMM: C[M,256] = A[M,256] @ Bt[256,256]^T, f16 out ---------
__global__ __launch_bounds__(256) void gemm_mfma(const unsigned short* __restrict__ A,
                                                 const unsigned short* __restrict__ Bt,
                                                 unsigned short* __restrict__ C, int M) {
    __shared__ unsigned short As[128 * 64];
    __shared__ unsigned short Bs[128 * 64];
    const int t = threadIdx.x;
    const int lane = t & 63, wid = t >> 6;
    const int wr = wid >> 1, wc = wid & 1;
    const int bm = blockIdx.x * 128;
    const int bn = blockIdx.y * 128;
    f32x4 acc[4][4] = {};
    const int lrow = t >> 3, lslot = t & 7;
    for (int k0 = 0; k0 < 256; k0 += 64) {
        __syncthreads();
#pragma unroll
        for (int i = 0; i < 4; ++i) {
            int row = lrow + 32 * i;
            int ga = bm + row; ga = ga < M ? ga : M - 1;
            uint4 av = *(const uint4*)(A + (size_t)ga * FDIM + k0 + lslot * 8);
            *(uint4*)(As + row * 64 + ((lslot ^ (row & 7)) << 3)) = av;
            uint4 bv = *(const uint4*)(Bt + (size_t)(bn + row) * FDIM + k0 + lslot * 8);
            *(uint4*)(Bs + row * 64 + ((lslot ^ (row & 7)) << 3)) = bv;
        }
        __syncthreads();
#pragma unroll
        for (int ks = 0; ks < 2; ++ks) {
            const int kq = ks * 4 + (lane >> 4);
            f16x8 a[4], b[4];
#pragma unroll
            for (int f = 0; f < 4; ++f) {
                int ra = wr * 64 + f * 16 + (lane & 15);
                a[f] = *(const f16x8*)(As + ra * 64 + ((kq ^ (ra & 7)) << 3));
                int rb = wc * 64 + f * 16 + (lane & 15);
                b[f] = *(const f16x8*)(Bs + rb * 64 + ((kq ^ (rb & 7)) << 3));
            }
#pragma unroll
            for (int mf = 0; mf < 4; ++mf)
#pragma unroll
                for (int nf = 0; nf < 4; ++nf)
                    acc[mf][nf] = __builtin_amdgcn_mfma_f32_16x16x32_f16(
                        a[mf], b[nf], acc[mf][nf], 0, 0, 0);
        }
    }
    const int col0 = bn + wc * 64 + (lane & 15);
    const int row00 = bm + wr * 64 + (lane >> 4) * 4;
#pragma unroll
    for (int mf = 0; mf < 4; ++mf)
#pragma unroll
        for (int nf = 0; nf < 4; ++nf) {
            f32x4 v = acc[mf][nf];
            int col = col0 + nf * 16;
#pragma unroll
            for (int r = 0; r < 4; ++r) {
                int row = row00 + mf * 16 + r;
                if (row < M) C[(size_t)row * FDIM + col] = f2h(v[r]);
            }
        }
}

// ------------- attention logits from f16 xp; wave per node -------------
template <int H>
__global__ __launch_bounds__(256) void aprep_k(const unsigned short* __restrict__ xp,
                                               const float* __restrict__ atts,
                                               const float* __restrict__ attd,
                                               float* __restrict__ as_,
                                               float* __restrict__ ad_) {
    const int lane = threadIdx.x & 63;
    const int n = blockIdx.x * 4 + (threadIdx.x >> 6);
    if (n >= NNODES) return;
    const int c = lane << 2;
    uint2 u = *(const uint2*)(xp + (size_t)n * FDIM + c);
    float v0 = hlo(u.x), v1 = hhi(u.x), v2 = hlo(u.y), v3 = hhi(u.y);
    float4 s4 = *(const float4*)(atts + c);
    float4 d4 = *(const float4*)(attd + c);
    float ss = v0 * s4.x + v1 * s4.y + v2 * s4.z + v3 * s4.w;
    float sd = v0 * d4.x + v1 * d4.y + v2 * d4.z + v3 * d4.w;
    constexpr int G = 64 / H;
#pragma unroll
    for (int off = 1; off < G; off <<= 1) {
        ss += __shfl_xor(ss, off);
        sd += __shfl_xor(sd, off);
    }
    if ((lane & (G - 1)) == 0) {
        int h = lane / G;
        as_[n * H + h] = ss;
        ad_[n * H + h] = sd;
    }
}

// ---------------- CSR build: histogram -> 3-phase scan -> scatter ----------------
__global__ __launch_bounds__(256) void hist_k(const int* __restrict__ ei,
                                              int* __restrict__ deg) {
    int e = blockIdx.x * 256 + threadIdx.x;
    if (e < NEDGES) atomicAdd(&deg[ei[NEDGES + e]], 1);
}

__global__ __launch_bounds__(256) void scanA_k(const int* __restrict__ deg,
                                               int* __restrict__ bsum) {
    const int b = blockIdx.x, t = threadIdx.x;
    const int i = b * SCAN_CHUNK + t;
    int v = (t < SCAN_CHUNK && i < NNODES) ? deg[i] : 0;
#pragma unroll
    for (int off = 1; off < 64; off <<= 1) v += __shfl_xor(v, off);
    __shared__ int ws[4];
    if ((t & 63) == 0) ws[t >> 6] = v;
    __syncthreads();
    if (t == 0) bsum[b] = ws[0] + ws[1] + ws[2] + ws[3];
}

__global__ __launch_bounds__(256) void scanB_k(const int* __restrict__ bsum,
                                               int* __restrict__ boff,
                                               int* __restrict__ rowptr) {
    const int t = threadIdx.x;
    const int lane = t & 63, wid = t >> 6;
    int orig = bsum[t];
    int v = orig;
#pragma unroll
    for (int off = 1; off < 64; off <<= 1) {
        int u = __shfl_up(v, off);
        if (lane >= off) v += u;
    }
    __shared__ int ws[4], wo[4];
    if (lane == 63) ws[wid] = v;
    __syncthreads();
    if (t == 0) {
        int a = 0;
        for (int k = 0; k < 4; ++k) { wo[k] = a; a += ws[k]; }
        rowptr[NNODES] = a;
    }
    __syncthreads();
    boff[t] = wo[wid] + v - orig;
}

__global__ __launch_bounds__(256) void scanC_k(const int* __restrict__ deg,
                                               const int* __restrict__ boff,
                                               int* __restrict__ rowptr) {
    const int b = blockIdx.x, t = threadIdx.x;
    const int i = b * SCAN_CHUNK + t;
    const bool ok = (t < SCAN_CHUNK && i < NNODES);
    int orig = ok ? deg[i] : 0;
    int v = orig;
    const int lane = t & 63, wid = t >> 6;
#pragma unroll
    for (int off = 1; off < 64; off <<= 1) {
        int u = __shfl_up(v, off);
        if (lane >= off) v += u;
    }
    __shared__ int ws[4], wo[4];
    if (lane == 63) ws[wid] = v;
    __syncthreads();
    if (t == 0) {
        int a = 0;
        for (int k = 0; k < 4; ++k) { wo[k] = a; a += ws[k]; }
    }
    __syncthreads();
    if (ok) rowptr[i] = boff[b] + wo[wid] + v - orig;
}

__global__ __launch_bounds__(256) void scatter_k(const int* __restrict__ ei,
                                                 const int* __restrict__ rowptr,
                                                 int* __restrict__ deg,
                                                 int* __restrict__ ssrc) {
    int e = blockIdx.x * 256 + threadIdx.x;
    if (e >= NEDGES) return;
    int s = ei[e], d = ei[NEDGES + e];
    int old = atomicSub(&deg[d], 1);
    ssrc[rowptr[d + 1] - old] = s;
}

// ---- layer-1 gather (H=4): prefetched strips, half-wave uint4, UNIFORM loops ----
__global__ __launch_bounds__(256) void gather1_k(const unsigned short* __restrict__ xp,
                                                 const float* __restrict__ as_,
                                                 const float* __restrict__ ad_,
                                                 const int* __restrict__ rowptr,
                                                 const int* __restrict__ ssrc,
                                                 const float* __restrict__ bias,
                                                 unsigned short* __restrict__ out) {
    const int lane = threadIdx.x & 63;
    const int n = blockIdx.x * 4 + (threadIdx.x >> 6);
    if (n >= NNODES) return;
    const int half = lane >> 5;         // edge parity for this half-wave
    const int fl = lane & 31;           // feature lane: 8 f16 feats
    const int c = fl << 3;
    const int h = fl >> 3;              // head of my feature chunk
    const int eloc = lane >> 2;         // weight strip: edge slot (0..15)
    const int hh = lane & 3;            // weight strip: head slot
    const float adW = ad_[n * 4 + hh];
    float a[8] = {};
    float den = 0.f;
    const int beg = rowptr[n], end = rowptr[n + 1];
    int sv = 0; float av = 0.f;
    {
        int e0 = beg + eloc;
        if (e0 < end) { sv = ssrc[e0]; av = as_[sv * 4 + hh]; }
    }
    for (int base = beg; base < end; base += 16) {
        float wv = (base + eloc < end) ? leaky_exp(av + adW) : 0.f;
        // prefetch next strip
        int sv_n = 0; float av_n = 0.f;
        {
            int nx = base + 16 + eloc;
            if (nx < end) { sv_n = ssrc[nx]; av_n = as_[sv_n * 4 + hh]; }
        }
        // strip denominator (uniform region)
        float dred = wv;
#pragma unroll
        for (int off = 4; off < 64; off <<= 1) dred += __shfl_xor(dred, off);
        den += __shfl(dred, h);
        const int cnt = min(16, end - base);
        int e = 0;
        // UNIFORM bound: idx = e + 2q + half covers [e, e+8) across both halves
        for (; e + 8 <= cnt; e += 8) {
            uint4 u[4]; float w[4];
#pragma unroll
            for (int q = 0; q < 4; ++q) {
                int idx = e + 2 * q + half;
                int sq = __shfl(sv, idx << 2);
                w[q] = __shfl(wv, (idx << 2) | h);
                u[q] = *(const uint4*)(xp + (((unsigned)sq << 8) + (unsigned)c));
            }
#pragma unroll
            for (int q = 0; q < 4; ++q) {
                a[0] = fmaf(hlo(u[q].x), w[q], a[0]);
                a[1] = fmaf(hhi(u[q].x), w[q], a[1]);
                a[2] = fmaf(hlo(u[q].y), w[q], a[2]);
                a[3] = fmaf(hhi(u[q].y), w[q], a[3]);
                a[4] = fmaf(hlo(u[q].z), w[q], a[4]);
                a[5] = fmaf(hhi(u[q].z), w[q], a[5]);
                a[6] = fmaf(hlo(u[q].w), w[q], a[6]);
                a[7] = fmaf(hhi(u[q].w), w[q], a[7]);
            }
        }
        // UNIFORM tail: shfls run on all 64 lanes; only consumption is guarded
        for (; e < cnt; e += 2) {
            int idx = e + half;
            int sq = __shfl(sv, idx << 2);
            float w0 = __shfl(wv, (idx << 2) | h);
            if (idx < cnt) {
                uint4 u0 = *(const uint4*)(xp + (((unsigned)sq << 8) + (unsigned)c));
                a[0] = fmaf(hlo(u0.x), w0, a[0]); a[1] = fmaf(hhi(u0.x), w0, a[1]);
                a[2] = fmaf(hlo(u0.y), w0, a[2]); a[3] = fmaf(hhi(u0.y), w0, a[3]);
                a[4] = fmaf(hlo(u0.z), w0, a[4]); a[5] = fmaf(hhi(u0.z), w0, a[5]);
                a[6] = fmaf(hlo(u0.w), w0, a[6]); a[7] = fmaf(hhi(u0.w), w0, a[7]);
            }
        }
        sv = sv_n; av = av_n;
    }
    // merge the two half-wave edge streams (uniform region)
#pragma unroll
    for (int j = 0; j < 8; ++j) a[j] += __shfl_xor(a[j], 32);
    {   // self loop
        float w = leaky_exp(as_[n * 4 + h] + ad_[n * 4 + h]);
        uint4 u = *(const uint4*)(xp + (((unsigned)n << 8) + (unsigned)c));
        a[0] = fmaf(hlo(u.x), w, a[0]); a[1] = fmaf(hhi(u.x), w, a[1]);
        a[2] = fmaf(hlo(u.y), w, a[2]); a[3] = fmaf(hhi(u.y), w, a[3]);
        a[4] = fmaf(hlo(u.z), w, a[4]); a[5] = fmaf(hhi(u.z), w, a[5]);
        a[6] = fmaf(hlo(u.w), w, a[6]); a[7] = fmaf(hhi(u.w), w, a[7]);
        den += w;
    }
    if (lane < 32) {
        const float inv = 1.f / (den + 1e-16f);
        float4 b0 = *(const float4*)(bias + c);
        float4 b1 = *(const float4*)(bias + c + 4);
        float o[8] = {a[0] * inv + b0.x, a[1] * inv + b0.y,
                      a[2] * inv + b0.z, a[3] * inv + b0.w,
                      a[4] * inv + b1.x, a[5] * inv + b1.y,
                      a[6] * inv + b1.z, a[7] * inv + b1.w};
        ushort8 r;
#pragma unroll
        for (int j = 0; j < 8; ++j) {
            float v = o[j] > 0.f ? o[j] : __expf(o[j]) - 1.f;
            r[j] = f2h(v);
        }
        *(ushort8*)(out + (size_t)n * FDIM + c) = r;
    }
}

// ---- layer-2 gather (H=1): prefetched strips, half-wave uint4, UNIFORM loops ----
__global__ __launch_bounds__(256) void gather2_k(const unsigned short* __restrict__ xp,
                                                 const float* __restrict__ as_,
                                                 const float* __restrict__ ad_,
                                                 const int* __restrict__ rowptr,
                                                 const int* __restrict__ ssrc,
                                                 const float* __restrict__ bias,
                                                 const float* __restrict__ bng,
                                                 const float* __restrict__ bnb,
                                                 const float* __restrict__ bnm,
                                                 const float* __restrict__ bnv,
                                                 const float* __restrict__ lng,
                                                 const float* __restrict__ lnb,
                                                 float* __restrict__ out) {
    const int lane = threadIdx.x & 63;
    const int n = blockIdx.x * 4 + (threadIdx.x >> 6);
    if (n >= NNODES) return;
    const int half = lane >> 5;
    const int fl = lane & 31;
    const int c = fl << 3;
    const float adn = ad_[n];
    float a[8] = {};
    float den = 0.f;
    const int beg = rowptr[n], end = rowptr[n + 1];
    int sv = 0; float av = 0.f;
    {
        int e0 = beg + lane;
        if (e0 < end) { sv = ssrc[e0]; av = as_[sv]; }
    }
    for (int base = beg; base < end; base += 64) {
        float wv = (base + lane < end) ? leaky_exp(av + adn) : 0.f;
        int sv_n = 0; float av_n = 0.f;
        {
            int nx = base + 64 + lane;
            if (nx < end) { sv_n = ssrc[nx]; av_n = as_[sv_n]; }
        }
        float dred = wv;
#pragma unroll
        for (int off = 1; off < 64; off <<= 1) dred += __shfl_xor(dred, off);
        den += dred;
        const int cnt = min(64, end - base);
        int e = 0;
        for (; e + 8 <= cnt; e += 8) {
            uint4 u[4]; float w[4];
#pragma unroll
            for (int q = 0; q < 4; ++q) {
                int idx = e + 2 * q + half;
                int sq = __shfl(sv, idx);
                w[q] = __shfl(wv, idx);
                u[q] = *(const uint4*)(xp + (((unsigned)sq << 8) + (unsigned)c));
            }
#pragma unroll
            for (int q = 0; q < 4; ++q) {
                a[0] = fmaf(hlo(u[q].x), w[q], a[0]);
                a[1] = fmaf(hhi(u[q].x), w[q], a[1]);
                a[2] = fmaf(hlo(u[q].y), w[q], a[2]);
                a[3] = fmaf(hhi(u[q].y), w[q], a[3]);
                a[4] = fmaf(hlo(u[q].z), w[q], a[4]);
                a[5] = fmaf(hhi(u[q].z), w[q], a[5]);
                a[6] = fmaf(hlo(u[q].w), w[q], a[6]);
                a[7] = fmaf(hhi(u[q].w), w[q], a[7]);
            }
        }
        for (; e < cnt; e += 2) {
            int idx = e + half;
            int sq = __shfl(sv, idx);
            float w0 = __shfl(wv, idx);
            if (idx < cnt) {
                uint4 u0 = *(const uint4*)(xp + (((unsigned)sq << 8) + (unsigned)c));
                a[0] = fmaf(hlo(u0.x), w0, a[0]); a[1] = fmaf(hhi(u0.x), w0, a[1]);
                a[2] = fmaf(hlo(u0.y), w0, a[2]); a[3] = fmaf(hhi(u0.y), w0, a[3]);
                a[4] = fmaf(hlo(u0.z), w0, a[4]); a[5] = fmaf(hhi(u0.z), w0, a[5]);
                a[6] = fmaf(hlo(u0.w), w0, a[6]); a[7] = fmaf(hhi(u0.w), w0, a[7]);
            }
        }
        sv = sv_n; av = av_n;
    }
#pragma unroll
    for (int j = 0; j < 8; ++j) a[j] += __shfl_xor(a[j], 32);
    {   // self loop
        float w = leaky_exp(as_[n] + adn);
        uint4 u = *(const uint4*)(xp + (((unsigned)n << 8) + (unsigned)c));
        a[0] = fmaf(hlo(u.x), w, a[0]); a[1] = fmaf(hhi(u.x), w, a[1]);
        a[2] = fmaf(hlo(u.y), w, a[2]); a[3] = fmaf(hhi(u.y), w, a[3]);
        a[4] = fmaf(hlo(u.z), w, a[4]); a[5] = fmaf(hhi(u.z), w, a[5]);
        a[6] = fmaf(hlo(u.w), w, a[6]); a[7] = fmaf(hhi(u.w), w, a[7]);
        den += w;
    }
    const float inv = 1.f / (den + 1e-16f);
    float vals[8];
    float4 bb0 = *(const float4*)(bias + c), bb1 = *(const float4*)(bias + c + 4);
    float4 bm0 = *(const float4*)(bnm + c),  bm1 = *(const float4*)(bnm + c + 4);
    float4 bv0 = *(const float4*)(bnv + c),  bv1 = *(const float4*)(bnv + c + 4);
    float4 bg0 = *(const float4*)(bng + c),  bg1 = *(const float4*)(bng + c + 4);
    float4 be0 = *(const float4*)(bnb + c),  be1 = *(const float4*)(bnb + c + 4);
    float bbv[8] = {bb0.x, bb0.y, bb0.z, bb0.w, bb1.x, bb1.y, bb1.z, bb1.w};
    float bmv[8] = {bm0.x, bm0.y, bm0.z, bm0.w, bm1.x, bm1.y, bm1.z, bm1.w};
    float bvv[8] = {bv0.x, bv0.y, bv0.z, bv0.w, bv1.x, bv1.y, bv1.z, bv1.w};
    float bgv[8] = {bg0.x, bg0.y, bg0.z, bg0.w, bg1.x, bg1.y, bg1.z, bg1.w};
    float bev[8] = {be0.x, be0.y, be0.z, be0.w, be1.x, be1.y, be1.z, be1.w};
#pragma unroll
    for (int j = 0; j < 8; ++j) {
        float o = a[j] * inv + bbv[j];
        o = o > 0.f ? o : __expf(o) - 1.f;                             // ELU
        o = (o - bmv[j]) * rsqrtf(bvv[j] + 1e-5f) * bgv[j] + bev[j];   // BN
        vals[j] = o;
    }
    float s1 = 0.f, s2 = 0.f;
#pragma unroll
    for (int j = 0; j < 8; ++j) { s1 += vals[j]; s2 += vals[j] * vals[j]; }
#pragma unroll
    for (int off = 1; off < 32; off <<= 1) {
        s1 += __shfl_xor(s1, off);
        s2 += __shfl_xor(s2, off);
    }
    if (lane < 32) {
        float mu  = s1 * (1.f / 256.f);
        float var = s2 * (1.f / 256.f) - mu * mu;
        float r   = rsqrtf(var + 1e-5f);
        float4 lg0 = *(const float4*)(lng + c), lg1 = *(const float4*)(lng + c + 4);
        float4 lb0 = *(const float4*)(lnb + c), lb1 = *(const float4*)(lnb + c + 4);
        float lgv[8] = {lg0.x, lg0.y, lg0.z, lg0.w, lg1.x, lg1.y, lg1.z, lg1.w};
        float lbv[8] = {lb0.x, lb0.y, lb0.z, lb0.w, lb1.x, lb1.y, lb1.z, lb1.w};
        float4 o0, o1;
        o0.x = (vals[0] - mu) * r * lgv[0] + lbv[0];
        o0.y = (vals[1] - mu) * r * lgv[1] + lbv[1];
        o0.z = (vals[2] - mu) * r * lgv[2] + lbv[2];
        o0.w = (vals[3] - mu) * r * lgv[3] + lbv[3];
        o1.x = (vals[4] - mu) * r * lgv[4] + lbv[4];
        o1.y = (vals[5] - mu) * r * lgv[5] + lbv[5];
        o1.z = (vals[6] - mu) * r * lgv[6] + lbv[6];
        o1.w = (vals[7] - mu) * r * lgv[7] + lbv[7];
        *(float4*)(out + (size_t)n * FDIM + c) = o0;
        *(float4*)(out + (size_t)n * FDIM + c + 4) = o1;
    }
}

extern "C" void kernel_launch(void* const* d_in, const int* in_sizes, int n_in,
                              void* d_out, int out_size, void* d_ws, size_t ws_size,
                              hipStream_t stream) {
    const float* x      = (const float*)d_in[0];
    const int*   ei     = (const int*)d_in[1];
    const float* W1     = (const float*)d_in[2];
    const float* atts1  = (const float*)d_in[3];
    const float* attd1  = (const float*)d_in[4];
    const float* bias1  = (const float*)d_in[5];
    const float* W2     = (const float*)d_in[6];
    const float* atts2  = (const float*)d_in[7];
    const float* attd2  = (const float*)d_in[8];
    const float* bias2  = (const float*)d_in[9];
    const float* bng    = (const float*)d_in[10];
    const float* bnb    = (const float*)d_in[11];
    const float* bnm    = (const float*)d_in[12];
    const float* bnv    = (const float*)d_in[13];
    const float* lng    = (const float*)d_in[14];
    const float* lnb    = (const float*)d_in[15];

    const size_t NF = (size_t)NNODES * FDIM;
    unsigned short* xpbf = (unsigned short*)d_ws;     // 25.6 MB (xp, both layers)
    unsigned short* xbf  = xpbf + NF;                 // 25.6 MB (x f16, then h1)
    unsigned short* wt1  = xbf + NF;
    unsigned short* wt2  = wt1 + 65536;
    float* as1   = (float*)(wt2 + 65536);
    float* ad1   = as1 + (size_t)NNODES * 4;
    float* as2   = ad1 + (size_t)NNODES * 4;
    float* ad2   = as2 + NNODES;
    int*   deg    = (int*)(ad2 + NNODES);
    int*   rowptr = deg + NNODES;
    int*   bsum   = rowptr + (NNODES + 1);
    int*   boff   = bsum + SCAN_BLOCKS;
    int*   ssrc   = boff + SCAN_BLOCKS;
    float* outf  = (float*)d_out;

    const dim3 gemm_grid((NNODES + 127) / 128, 2);
    const int node_wave_blocks = (NNODES + 3) / 4;
    const int edge_thread_blocks = (NEDGES + 255) / 256;
    const int cvt_blocks = (int)((NF / 8 + 255) / 256);

    // ---- prep: conversions + CSR ----
    cvt_k<<<cvt_blocks, 256, 0, stream>>>(x, xbf, (int)(NF / 8));
    wprep_k<<<256, 256, 0, stream>>>(W1, wt1);
    wprep_k<<<256, 256, 0, stream>>>(W2, wt2);
    hipMemsetAsync(deg, 0, NNODES * sizeof(int), stream);
    hist_k<<<edge_thread_blocks, 256, 0, stream>>>(ei, deg);
    scanA_k<<<SCAN_BLOCKS, 256, 0, stream>>>(deg, bsum);
    scanB_k<<<1, 256, 0, stream>>>(bsum, boff, rowptr);
    scanC_k<<<SCAN_BLOCKS, 256, 0, stream>>>(deg, boff, rowptr);
    scatter_k<<<edge_thread_blocks, 256, 0, stream>>>(ei, rowptr, deg, ssrc);

    // ---- layer 1 ----
    gemm_mfma<<<gemm_grid, 256, 0, stream>>>(xbf, wt1, xpbf, NNODES);
    aprep_k<4><<<node_wave_blocks, 256, 0, stream>>>(xpbf, atts1, attd1, as1, ad1);
    gather1_k<<<node_wave_blocks, 256, 0, stream>>>(xpbf, as1, ad1, rowptr, ssrc,
                                                    bias1, xbf);

    // ---- layer 2 ----
    gemm_mfma<<<gemm_grid, 256, 0, stream>>>(xbf, wt2, xpbf, NNODES);
    aprep_k<1><<<node_wave_blocks, 256, 0, stream>>>(xpbf, atts2, attd2, as2, ad2);
    gather2_k<<<node_wave_blocks, 256, 0, stream>>>(xpbf, as2, ad2, rowptr, ssrc,
                                                    bias2, bng, bnb, bnm, bnv,
                                                    lng, lnb, outf);
}

// Round 12
// 290.826 us; speedup vs baseline: 1.0378x; 1.0032x over previous
//
#include <hip/hip_runtime.h>
#include <cstddef>
#include <cstdint>

#define NNODES 50000
#define NEDGES 800000
#define FDIM   256

#define SCAN_BLOCKS 256
#define SCAN_CHUNK  ((NNODES + SCAN_BLOCKS - 1) / SCAN_BLOCKS)   // 196

typedef __attribute__((ext_vector_type(8))) _Float16 f16x8;
typedef __attribute__((ext_vector_type(8))) unsigned short ushort8;
typedef __attribute__((ext_vector_type(4))) float f32x4;

__device__ __forceinline__ float leaky_exp(float a) {
    float e = a > 0.f ? a : 0.2f * a;
    return __expf(e);
}
__device__ __forceinline__ unsigned short f2h(float f) {
    return __builtin_bit_cast(unsigned short, (_Float16)f);
}
__device__ __forceinline__ float hlo(uint32_t u) {
    _Float16 h = __builtin_bit_cast(_Float16, (unsigned short)(u & 0xffffu));
    return (float)h;
}
__device__ __forceinline__ float hhi(uint32_t u) {
    _Float16 h = __builtin_bit_cast(_Float16, (unsigned short)(u >> 16));
    return (float)h;
}
__device__ __forceinline__ float rlanef(float v, int l) {
    return __builtin_bit_cast(float,
        __builtin_amdgcn_readlane(__builtin_bit_cast(int, v), l));
}

// --- W[256][256] -> Wt[n][k] f16 (transpose + convert); blockIdx.y picks W1/W2 ---
__global__ __launch_bounds__(256) void wprep_k(const float* __restrict__ W1,
                                               unsigned short* __restrict__ Wt1,
                                               const float* __restrict__ W2,
                                               unsigned short* __restrict__ Wt2) {
    const float* W = blockIdx.y ? W2 : W1;
    unsigned short* Wt = blockIdx.y ? Wt2 : Wt1;
    int n = blockIdx.x, k = threadIdx.x;
    Wt[n * 256 + k] = f2h(W[k * 256 + n]);
}

// --------- f16 MFMA GEMM: C[M,256] = A[M,256] @ Bt[256,256]^T, f16 out ---------
// AFP32: A is fp32, converted during LDS staging (layer 1).
// FUSE_LOGITS (requires grid.y=2, H=4 layout): per-row per-head attention
// logits computed from f32 accumulators, direct store (no atomics).
template <bool AFP32, bool FUSE_LOGITS>
__global__ __launch_bounds__(256) void gemm_mfma(const void* __restrict__ Aab,
                                                 const unsigned short* __restrict__ Bt,
                                                 unsigned short* __restrict__ C,
                                                 const float* __restrict__ atts,
                                                 const float* __restrict__ attd,
                                                 float* __restrict__ as_,
                                                 float* __restrict__ ad_,
                                                 int M) {
    __shared__ unsigned short As[128 * 64];
    __shared__ unsigned short Bs[128 * 64];
    const int t = threadIdx.x;
    const int lane = t & 63, wid = t >> 6;
    const int wr = wid >> 1, wc = wid & 1;
    const int bm = blockIdx.x * 128;
    const int bny = blockIdx.y;
    const int bn = bny * 128;
    f32x4 acc[4][4] = {};
    const int lrow = t >> 3, lslot = t & 7;
    for (int k0 = 0; k0 < 256; k0 += 64) {
        __syncthreads();
#pragma unroll
        for (int i = 0; i < 4; ++i) {
            int row = lrow + 32 * i;
            int ga = bm + row; ga = ga < M ? ga : M - 1;
            if (AFP32) {
                const float* p = (const float*)Aab + (size_t)ga * FDIM + k0 + lslot * 8;
                float4 f0 = *(const float4*)p;
                float4 f1 = *(const float4*)(p + 4);
                ushort8 r;
                r[0] = f2h(f0.x); r[1] = f2h(f0.y); r[2] = f2h(f0.z); r[3] = f2h(f0.w);
                r[4] = f2h(f1.x); r[5] = f2h(f1.y); r[6] = f2h(f1.z); r[7] = f2h(f1.w);
                *(ushort8*)(As + row * 64 + ((lslot ^ (row & 7)) << 3)) = r;
            } else {
                const unsigned short* A16 = (const unsigned short*)Aab;
                uint4 av = *(const uint4*)(A16 + (size_t)ga * FDIM + k0 + lslot * 8);
                *(uint4*)(As + row * 64 + ((lslot ^ (row & 7)) << 3)) = av;
            }
            uint4 bv = *(const uint4*)(Bt + (size_t)(bn + row) * FDIM + k0 + lslot * 8);
            *(uint4*)(Bs + row * 64 + ((lslot ^ (row & 7)) << 3)) = bv;
        }
        __syncthreads();
#pragma unroll
        for (int ks = 0; ks < 2; ++ks) {
            const int kq = ks * 4 + (lane >> 4);
            f16x8 a[4], b[4];
#pragma unroll
            for (int f = 0; f < 4; ++f) {
                int ra = wr * 64 + f * 16 + (lane & 15);
                a[f] = *(const f16x8*)(As + ra * 64 + ((kq ^ (ra & 7)) << 3));
                int rb = wc * 64 + f * 16 + (lane & 15);
                b[f] = *(const f16x8*)(Bs + rb * 64 + ((kq ^ (rb & 7)) << 3));
            }
#pragma unroll
            for (int mf = 0; mf < 4; ++mf)
#pragma unroll
                for (int nf = 0; nf < 4; ++nf)
                    acc[mf][nf] = __builtin_amdgcn_mfma_f32_16x16x32_f16(
                        a[mf], b[nf], acc[mf][nf], 0, 0, 0);
        }
    }
    const int col0 = bn + wc * 64 + (lane & 15);
    const int row00 = bm + wr * 64 + (lane >> 4) * 4;
    if (FUSE_LOGITS) {
        // head = global_col/64 = 2*bny + wc; its 64 cols live wholly in this wave.
        const int head = 2 * bny + wc;
        float sv4[4], dv4[4];
#pragma unroll
        for (int nf = 0; nf < 4; ++nf) {
            sv4[nf] = atts[col0 + nf * 16];
            dv4[nf] = attd[col0 + nf * 16];
        }
#pragma unroll
        for (int mf = 0; mf < 4; ++mf)
#pragma unroll
            for (int r = 0; r < 4; ++r) {
                float ps = 0.f, pd = 0.f;
#pragma unroll
                for (int nf = 0; nf < 4; ++nf) {
                    float v = acc[mf][nf][r];
                    ps = fmaf(v, sv4[nf], ps);
                    pd = fmaf(v, dv4[nf], pd);
                }
#pragma unroll
                for (int off = 1; off < 16; off <<= 1) {
                    ps += __shfl_xor(ps, off);
                    pd += __shfl_xor(pd, off);
                }
                int row = row00 + mf * 16 + r;
                if ((lane & 15) == 0 && row < M) {
                    as_[row * 4 + head] = ps;
                    ad_[row * 4 + head] = pd;
                }
            }
    }
#pragma unroll
    for (int mf = 0; mf < 4; ++mf)
#pragma unroll
        for (int nf = 0; nf < 4; ++nf) {
            f32x4 v = acc[mf][nf];
            int col = col0 + nf * 16;
#pragma unroll
            for (int r = 0; r < 4; ++r) {
                int row = row00 + mf * 16 + r;
                if (row < M) C[(size_t)row * FDIM + col] = f2h(v[r]);
            }
        }
}

// ------------- attention logits from f16 xp; wave per node (layer 2) -------------
template <int H>
__global__ __launch_bounds__(256) void aprep_k(const unsigned short* __restrict__ xp,
                                               const float* __restrict__ atts,
                                               const float* __restrict__ attd,
                                               float* __restrict__ as_,
                                               float* __restrict__ ad_) {
    const int lane = threadIdx.x & 63;
    const int n = blockIdx.x * 4 + (threadIdx.x >> 6);
    if (n >= NNODES) return;
    const int c = lane << 2;
    uint2 u = *(const uint2*)(xp + (size_t)n * FDIM + c);
    float v0 = hlo(u.x), v1 = hhi(u.x), v2 = hlo(u.y), v3 = hhi(u.y);
    float4 s4 = *(const float4*)(atts + c);
    float4 d4 = *(const float4*)(attd + c);
    float ss = v0 * s4.x + v1 * s4.y + v2 * s4.z + v3 * s4.w;
    float sd = v0 * d4.x + v1 * d4.y + v2 * d4.z + v3 * d4.w;
    constexpr int G = 64 / H;
#pragma unroll
    for (int off = 1; off < G; off <<= 1) {
        ss += __shfl_xor(ss, off);
        sd += __shfl_xor(sd, off);
    }
    if ((lane & (G - 1)) == 0) {
        int h = lane / G;
        as_[n * H + h] = ss;
        ad_[n * H + h] = sd;
    }
}

// ---------------- CSR build: histogram -> 3-phase scan -> scatter ----------------
__global__ __launch_bounds__(256) void hist_k(const int* __restrict__ ei,
                                              int* __restrict__ deg) {
    int e = blockIdx.x * 256 + threadIdx.x;
    if (e < NEDGES) atomicAdd(&deg[ei[NEDGES + e]], 1);
}

__global__ __launch_bounds__(256) void scanA_k(const int* __restrict__ deg,
                                               int* __restrict__ bsum) {
    const int b = blockIdx.x, t = threadIdx.x;
    const int i = b * SCAN_CHUNK + t;
    int v = (t < SCAN_CHUNK && i < NNODES) ? deg[i] : 0;
#pragma unroll
    for (int off = 1; off < 64; off <<= 1) v += __shfl_xor(v, off);
    __shared__ int ws[4];
    if ((t & 63) == 0) ws[t >> 6] = v;
    __syncthreads();
    if (t == 0) bsum[b] = ws[0] + ws[1] + ws[2] + ws[3];
}

__global__ __launch_bounds__(256) void scanB_k(const int* __restrict__ bsum,
                                               int* __restrict__ boff,
                                               int* __restrict__ rowptr) {
    const int t = threadIdx.x;
    const int lane = t & 63, wid = t >> 6;
    int orig = bsum[t];
    int v = orig;
#pragma unroll
    for (int off = 1; off < 64; off <<= 1) {
        int u = __shfl_up(v, off);
        if (lane >= off) v += u;
    }
    __shared__ int ws[4], wo[4];
    if (lane == 63) ws[wid] = v;
    __syncthreads();
    if (t == 0) {
        int a = 0;
        for (int k = 0; k < 4; ++k) { wo[k] = a; a += ws[k]; }
        rowptr[NNODES] = a;
    }
    __syncthreads();
    boff[t] = wo[wid] + v - orig;
}

__global__ __launch_bounds__(256) void scanC_k(const int* __restrict__ deg,
                                               const int* __restrict__ boff,
                                               int* __restrict__ rowptr) {
    const int b = blockIdx.x, t = threadIdx.x;
    const int i = b * SCAN_CHUNK + t;
    const bool ok = (t < SCAN_CHUNK && i < NNODES);
    int orig = ok ? deg[i] : 0;
    int v = orig;
    const int lane = t & 63, wid = t >> 6;
#pragma unroll
    for (int off = 1; off < 64; off <<= 1) {
        int u = __shfl_up(v, off);
        if (lane >= off) v += u;
    }
    __shared__ int ws[4], wo[4];
    if (lane == 63) ws[wid] = v;
    __syncthreads();
    if (t == 0) {
        int a = 0;
        for (int k = 0; k < 4; ++k) { wo[k] = a; a += ws[k]; }
    }
    __syncthreads();
    if (ok) rowptr[i] = boff[b] + wo[wid] + v - orig;
}

__global__ __launch_bounds__(256) void scatter_k(const int* __restrict__ ei,
                                                 const int* __restrict__ rowptr,
                                                 int* __restrict__ deg,
                                                 int* __restrict__ ssrc) {
    int e = blockIdx.x * 256 + threadIdx.x;
    if (e >= NEDGES) return;
    int s = ei[e], d = ei[NEDGES + e];
    int old = atomicSub(&deg[d], 1);
    ssrc[rowptr[d + 1] - old] = s;
}

// ---- layer-1 gather (H=4): f16 rows, den in weight phase, bias+ELU, f16 out ----
__global__ __launch_bounds__(256) void gather1_k(const unsigned short* __restrict__ xp,
                                                 const float* __restrict__ as_,
                                                 const float* __restrict__ ad_,
                                                 const int* __restrict__ rowptr,
                                                 const int* __restrict__ ssrc,
                                                 const float* __restrict__ bias,
                                                 unsigned short* __restrict__ out) {
    const int lane = threadIdx.x & 63;
    const int n = blockIdx.x * 4 + (threadIdx.x >> 6);
    if (n >= NNODES) return;
    const int h = lane >> 4;            // head for feature lanes
    const int c = lane << 2;
    const int eloc = lane >> 2;         // strip edge slot (0..15)
    const int hh = lane & 3;            // strip head slot
    const float adW = ad_[n * 4 + hh];
    float a0 = 0.f, a1 = 0.f, a2 = 0.f, a3 = 0.f, den = 0.f;
    const int beg = rowptr[n], end = rowptr[n + 1];
    for (int base = beg; base < end; base += 16) {
        int my_e = base + eloc;
        float wv = 0.f; int sv = 0;
        if (my_e < end) {
            sv = ssrc[my_e];
            wv = leaky_exp(as_[sv * 4 + hh] + adW);
        }
        float dred = wv;
#pragma unroll
        for (int off = 4; off < 64; off <<= 1) dred += __shfl_xor(dred, off);
        den += __shfl(dred, h);
        const int cnt = min(16, end - base);
        int e = 0;
        for (; e + 8 <= cnt; e += 8) {
            uint2 u[8]; float w[8];
#pragma unroll
            for (int q = 0; q < 8; ++q) {
                int sq = __builtin_amdgcn_readlane(sv, (e + q) << 2);
                u[q] = *(const uint2*)(xp + (((unsigned)sq << 8) + (unsigned)c));
                w[q] = __shfl(wv, ((e + q) << 2) | h);
            }
#pragma unroll
            for (int q = 0; q < 8; ++q) {
                a0 = fmaf(hlo(u[q].x), w[q], a0);
                a1 = fmaf(hhi(u[q].x), w[q], a1);
                a2 = fmaf(hlo(u[q].y), w[q], a2);
                a3 = fmaf(hhi(u[q].y), w[q], a3);
            }
        }
        for (; e < cnt; ++e) {
            int sq = __builtin_amdgcn_readlane(sv, e << 2);
            uint2 u0 = *(const uint2*)(xp + (((unsigned)sq << 8) + (unsigned)c));
            float w0 = __shfl(wv, (e << 2) | h);
            a0 = fmaf(hlo(u0.x), w0, a0); a1 = fmaf(hhi(u0.x), w0, a1);
            a2 = fmaf(hlo(u0.y), w0, a2); a3 = fmaf(hhi(u0.y), w0, a3);
        }
    }
    {   // self loop
        float w = leaky_exp(as_[n * 4 + h] + ad_[n * 4 + h]);
        uint2 u = *(const uint2*)(xp + (((unsigned)n << 8) + (unsigned)c));
        a0 = fmaf(hlo(u.x), w, a0); a1 = fmaf(hhi(u.x), w, a1);
        a2 = fmaf(hlo(u.y), w, a2); a3 = fmaf(hhi(u.y), w, a3);
        den += w;
    }
    const float inv = 1.f / (den + 1e-16f);
    float4 b4 = *(const float4*)(bias + c);
    float o[4] = {a0 * inv + b4.x, a1 * inv + b4.y,
                  a2 * inv + b4.z, a3 * inv + b4.w};
#pragma unroll
    for (int j = 0; j < 4; ++j) o[j] = o[j] > 0.f ? o[j] : __expf(o[j]) - 1.f;
    ushort4 r;
    r.x = f2h(o[0]); r.y = f2h(o[1]); r.z = f2h(o[2]); r.w = f2h(o[3]);
    *(ushort4*)(out + (size_t)n * FDIM + c) = r;
}

// ---- layer-2 gather (H=1): 64-edge strips, readlane weights; +BN+LN ----
__global__ __launch_bounds__(256) void gather2_k(const unsigned short* __restrict__ xp,
                                                 const float* __restrict__ as_,
                                                 const float* __restrict__ ad_,
                                                 const int* __restrict__ rowptr,
                                                 const int* __restrict__ ssrc,
                                                 const float* __restrict__ bias,
                                                 const float* __restrict__ bng,
                                                 const float* __restrict__ bnb,
                                                 const float* __restrict__ bnm,
                                                 const float* __restrict__ bnv,
                                                 const float* __restrict__ lng,
                                                 const float* __restrict__ lnb,
                                                 float* __restrict__ out) {
    const int lane = threadIdx.x & 63;
    const int n = blockIdx.x * 4 + (threadIdx.x >> 6);
    if (n >= NNODES) return;
    const int c = lane << 2;
    const float adn = ad_[n];
    float a0 = 0.f, a1 = 0.f, a2 = 0.f, a3 = 0.f, den = 0.f;
    const int beg = rowptr[n], end = rowptr[n + 1];
    for (int base = beg; base < end; base += 64) {
        int my_e = base + lane;
        float wv = 0.f; int sv = 0;
        if (my_e < end) {
            sv = ssrc[my_e];
            wv = leaky_exp(as_[sv] + adn);
        }
        float dred = wv;
#pragma unroll
        for (int off = 1; off < 64; off <<= 1) dred += __shfl_xor(dred, off);
        den += dred;
        const int cnt = min(64, end - base);
        int e = 0;
        for (; e + 8 <= cnt; e += 8) {
            uint2 u[8]; float w[8];
#pragma unroll
            for (int q = 0; q < 8; ++q) {
                int sq = __builtin_amdgcn_readlane(sv, e + q);
                u[q] = *(const uint2*)(xp + (((unsigned)sq << 8) + (unsigned)c));
                w[q] = rlanef(wv, e + q);
            }
#pragma unroll
            for (int q = 0; q < 8; ++q) {
                a0 = fmaf(hlo(u[q].x), w[q], a0);
                a1 = fmaf(hhi(u[q].x), w[q], a1);
                a2 = fmaf(hlo(u[q].y), w[q], a2);
                a3 = fmaf(hhi(u[q].y), w[q], a3);
            }
        }
        for (; e < cnt; ++e) {
            int sq = __builtin_amdgcn_readlane(sv, e);
            uint2 u0 = *(const uint2*)(xp + (((unsigned)sq << 8) + (unsigned)c));
            float w0 = rlanef(wv, e);
            a0 = fmaf(hlo(u0.x), w0, a0); a1 = fmaf(hhi(u0.x), w0, a1);
            a2 = fmaf(hlo(u0.y), w0, a2); a3 = fmaf(hhi(u0.y), w0, a3);
        }
    }
    {   // self loop
        float w = leaky_exp(as_[n] + adn);
        uint2 u = *(const uint2*)(xp + (((unsigned)n << 8) + (unsigned)c));
        a0 = fmaf(hlo(u.x), w, a0); a1 = fmaf(hhi(u.x), w, a1);
        a2 = fmaf(hlo(u.y), w, a2); a3 = fmaf(hhi(u.y), w, a3);
        den += w;
    }
    const float inv = 1.f / (den + 1e-16f);
    float vals[4] = {a0 * inv, a1 * inv, a2 * inv, a3 * inv};
#pragma unroll
    for (int j = 0; j < 4; ++j) {
        float o = vals[j] + bias[c + j];
        o = o > 0.f ? o : __expf(o) - 1.f;                             // ELU
        o = (o - bnm[c + j]) * rsqrtf(bnv[c + j] + 1e-5f) * bng[c + j]
            + bnb[c + j];                                              // BN
        vals[j] = o;
    }
    float s1 = vals[0] + vals[1] + vals[2] + vals[3];
    float s2 = vals[0] * vals[0] + vals[1] * vals[1] +
               vals[2] * vals[2] + vals[3] * vals[3];
#pragma unroll
    for (int off = 1; off < 64; off <<= 1) {
        s1 += __shfl_xor(s1, off);
        s2 += __shfl_xor(s2, off);
    }
    float mu  = s1 * (1.f / 256.f);
    float var = s2 * (1.f / 256.f) - mu * mu;
    float r   = rsqrtf(var + 1e-5f);
#pragma unroll
    for (int j = 0; j < 4; ++j)
        out[(size_t)n * FDIM + c + j] = (vals[j] - mu) * r * lng[c + j] + lnb[c + j];
}

extern "C" void kernel_launch(void* const* d_in, const int* in_sizes, int n_in,
                              void* d_out, int out_size, void* d_ws, size_t ws_size,
                              hipStream_t stream) {
    const float* x      = (const float*)d_in[0];
    const int*   ei     = (const int*)d_in[1];
    const float* W1     = (const float*)d_in[2];
    const float* atts1  = (const float*)d_in[3];
    const float* attd1  = (const float*)d_in[4];
    const float* bias1  = (const float*)d_in[5];
    const float* W2     = (const float*)d_in[6];
    const float* atts2  = (const float*)d_in[7];
    const float* attd2  = (const float*)d_in[8];
    const float* bias2  = (const float*)d_in[9];
    const float* bng    = (const float*)d_in[10];
    const float* bnb    = (const float*)d_in[11];
    const float* bnm    = (const float*)d_in[12];
    const float* bnv    = (const float*)d_in[13];
    const float* lng    = (const float*)d_in[14];
    const float* lnb    = (const float*)d_in[15];

    const size_t NF = (size_t)NNODES * FDIM;
    unsigned short* xpbf = (unsigned short*)d_ws;     // 25.6 MB (xp, both layers)
    unsigned short* xbf  = xpbf + NF;                 // 25.6 MB (h1 f16)
    unsigned short* wt1  = xbf + NF;
    unsigned short* wt2  = wt1 + 65536;
    float* as1   = (float*)(wt2 + 65536);
    float* ad1   = as1 + (size_t)NNODES * 4;
    float* as2   = ad1 + (size_t)NNODES * 4;
    float* ad2   = as2 + NNODES;
    int*   deg    = (int*)(ad2 + NNODES);
    int*   rowptr = deg + NNODES;
    int*   bsum   = rowptr + (NNODES + 1);
    int*   boff   = bsum + SCAN_BLOCKS;
    int*   ssrc   = boff + SCAN_BLOCKS;
    float* outf  = (float*)d_out;

    const dim3 gemm_grid((NNODES + 127) / 128, 2);
    const int node_wave_blocks = (NNODES + 3) / 4;
    const int edge_thread_blocks = (NEDGES + 255) / 256;

    // ---- prep: W transpose/convert + CSR ----
    wprep_k<<<dim3(256, 2), 256, 0, stream>>>(W1, wt1, W2, wt2);
    hipMemsetAsync(deg, 0, NNODES * sizeof(int), stream);
    hist_k<<<edge_thread_blocks, 256, 0, stream>>>(ei, deg);
    scanA_k<<<SCAN_BLOCKS, 256, 0, stream>>>(deg, bsum);
    scanB_k<<<1, 256, 0, stream>>>(bsum, boff, rowptr);
    scanC_k<<<SCAN_BLOCKS, 256, 0, stream>>>(deg, boff, rowptr);
    scatter_k<<<edge_thread_blocks, 256, 0, stream>>>(ei, rowptr, deg, ssrc);

    // ---- layer 1: GEMM reads fp32 x directly, fused H=4 logits (no atomics) ----
    gemm_mfma<true, true><<<gemm_grid, 256, 0, stream>>>(
        x, wt1, xpbf, atts1, attd1, as1, ad1, NNODES);
    gather1_k<<<node_wave_blocks, 256, 0, stream>>>(xpbf, as1, ad1, rowptr, ssrc,
                                                    bias1, xbf);

    // ---- layer 2: GEMM (f16 A = h1), standalone aprep (H=1 spans col-blocks) ----
    gemm_mfma<false, false><<<gemm_grid, 256, 0, stream>>>(
        xbf, wt2, xpbf, nullptr, nullptr, nullptr, nullptr, NNODES);
    aprep_k<1><<<node_wave_blocks, 256, 0, stream>>>(xpbf, atts2, attd2, as2, ad2);
    gather2_k<<<node_wave_blocks, 256, 0, stream>>>(xpbf, as2, ad2, rowptr, ssrc,
                                                    bias2, bng, bnb, bnm, bnv,
                                                    lng, lnb, outf);
}